// Round 2
// baseline (229.132 us; speedup 1.0000x reference)
//
#include <hip/hip_runtime.h>
#include <hip/hip_bf16.h>

#define DIN 768
#define DD  64
#define NB  8
#define SS  2048
#define NROWS (NB*SS)   // 16384

typedef __bf16 bf16;
typedef __attribute__((ext_vector_type(8))) __bf16 bf16x8;
typedef __attribute__((ext_vector_type(4))) __bf16 bf16x4;
typedef __attribute__((ext_vector_type(4))) float f32x4;

#define MFMA16 __builtin_amdgcn_mfma_f32_16x16x32_bf16

// ---------------------------------------------------------------------------
// ws layout (bf16 elements):
//   wt : [3][64][768]      transposed+converted weights      (147456 elems)
//   qn : [16384][64]       normalized q, scaled by log2e/8   (1048576)
//   kn : [16384][64]       normalized k                      (1048576)
//   vT : [8][64][2048]     v transposed per batch            (1048576)
// total = 3293184 elems = 6586368 bytes
// ---------------------------------------------------------------------------

// Transpose + convert W [768][64] f32 -> Wt [64][768] bf16.
// grid (12, 3): 12 k-tiles of 64, 3 tensors. LDS tile transpose so both the
// global read (f32x4) and the global write (bf16x4) are coalesced.
__global__ __launch_bounds__(256) void k_wt(const float* __restrict__ Wq,
                                            const float* __restrict__ Wk,
                                            const float* __restrict__ Wv,
                                            bf16* __restrict__ wt)
{
    int t = blockIdx.y;
    const float* W = (t == 0) ? Wq : ((t == 1) ? Wk : Wv);
    bf16* o = wt + (size_t)t * DD * DIN;
    int k0 = blockIdx.x * 64;

    __shared__ float tile[64][65];   // [col][k], pad 65 to break bank stride

    #pragma unroll
    for (int i = 0; i < 4; ++i) {
        int idx = threadIdx.x + i * 256;      // 0..1023
        int row = idx >> 4;                   // k within tile
        int c4  = (idx & 15) * 4;             // col group
        f32x4 u = *(const f32x4*)(W + (size_t)(k0 + row) * DD + c4);
        tile[c4 + 0][row] = u[0]; tile[c4 + 1][row] = u[1];
        tile[c4 + 2][row] = u[2]; tile[c4 + 3][row] = u[3];
    }
    __syncthreads();
    #pragma unroll
    for (int i = 0; i < 4; ++i) {
        int idx = threadIdx.x + i * 256;      // 0..1023
        int col = idx >> 4;
        int k4  = (idx & 15) * 4;
        bf16x4 u;
        u[0] = (bf16)tile[col][k4 + 0]; u[1] = (bf16)tile[col][k4 + 1];
        u[2] = (bf16)tile[col][k4 + 2]; u[3] = (bf16)tile[col][k4 + 3];
        *(bf16x4*)(o + (size_t)col * DIN + k0 + k4) = u;
    }
}

// Projection: X[16384][768] @ W[768][64] + b, then (q,k) row-L2-normalize,
// q additionally scaled by log2(e)/8 (folds cosine-attn scale + exp2 base).
// BM=64 rows/block, 4 waves x 16 rows, register-only MFMA (no LDS for q/k).
__global__ __launch_bounds__(256) void k_proj(
    const float* __restrict__ Xq, const float* __restrict__ Xk, const float* __restrict__ Xv,
    const float* __restrict__ bq, const float* __restrict__ bk, const float* __restrict__ bv,
    const bf16* __restrict__ wt,
    bf16* __restrict__ qn, bf16* __restrict__ kn, bf16* __restrict__ vT)
{
    int t = blockIdx.y;
    const float* X    = (t == 0) ? Xq : ((t == 1) ? Xk : Xv);
    const float* bias = (t == 0) ? bq : ((t == 1) ? bk : bv);
    const bf16*  w    = wt + (size_t)t * DD * DIN;

    int row0 = blockIdx.x * 64;
    int lane = threadIdx.x & 63;
    int wid  = threadIdx.x >> 6;
    int lr = lane & 15, lk = lane >> 4;
    int r  = row0 + wid * 16 + lr;          // A-fragment row

    const float* xp = X + (size_t)r * DIN + lk * 8;
    const bf16*  wp = w + (size_t)lr * DIN + lk * 8;

    f32x4 acc[4] = {};   // 4 col-fragments of 16 (N=64)

    #pragma unroll 4
    for (int kk = 0; kk < DIN; kk += 32) {
        f32x4 x0 = *(const f32x4*)(xp + kk);
        f32x4 x1 = *(const f32x4*)(xp + kk + 4);
        bf16x8 a;
        a[0] = (bf16)x0[0]; a[1] = (bf16)x0[1]; a[2] = (bf16)x0[2]; a[3] = (bf16)x0[3];
        a[4] = (bf16)x1[0]; a[5] = (bf16)x1[1]; a[6] = (bf16)x1[2]; a[7] = (bf16)x1[3];
        #pragma unroll
        for (int cf = 0; cf < 4; ++cf) {
            bf16x8 bfr = *(const bf16x8*)(wp + (size_t)cf * 16 * DIN + kk);
            acc[cf] = MFMA16(a, bfr, acc[cf], 0, 0, 0);
        }
    }

    // bias add (col = cf*16 + lr per C layout)
    #pragma unroll
    for (int cf = 0; cf < 4; ++cf) {
        float bc = bias[cf * 16 + lr];
        acc[cf][0] += bc; acc[cf][1] += bc; acc[cf][2] += bc; acc[cf][3] += bc;
    }

    if (t < 2) {
        // row L2 norm: C row = lk*4+reg, cols spread over (lr, cf)
        const float c = (t == 0) ? 0.18033688011112042f /* log2(e)/8 */ : 1.0f;
        f32x4 ss = {};
        #pragma unroll
        for (int cf = 0; cf < 4; ++cf)
            #pragma unroll
            for (int reg = 0; reg < 4; ++reg)
                ss[reg] += acc[cf][reg] * acc[cf][reg];
        #pragma unroll
        for (int reg = 0; reg < 4; ++reg) {
            float v = ss[reg];
            v += __shfl_xor(v, 1); v += __shfl_xor(v, 2);
            v += __shfl_xor(v, 4); v += __shfl_xor(v, 8);
            ss[reg] = v;
        }
        bf16* o = (t == 0) ? qn : kn;
        #pragma unroll
        for (int reg = 0; reg < 4; ++reg) {
            float sc = __builtin_amdgcn_rsqf(ss[reg]) * c;
            int rr = row0 + wid * 16 + lk * 4 + reg;
            #pragma unroll
            for (int cf = 0; cf < 4; ++cf)
                o[(size_t)rr * DD + cf * 16 + lr] = (bf16)(acc[cf][reg] * sc);
        }
    } else {
        // v: transpose through LDS, store vT[b][dv][s] coalesced
        __shared__ bf16 vt[64][72];   // pad 72 -> 144B stride, 8B aligned
        #pragma unroll
        for (int reg = 0; reg < 4; ++reg)
            #pragma unroll
            for (int cf = 0; cf < 4; ++cf)
                vt[cf * 16 + lr][wid * 16 + lk * 4 + reg] = (bf16)acc[cf][reg];
        __syncthreads();
        int bb = row0 >> 11, s0 = row0 & (SS - 1);
        #pragma unroll
        for (int j = 0; j < 4; ++j) {
            int f4 = threadIdx.x + j * 256;   // 0..1023, 4 elems each
            int dv = f4 >> 4, s4 = f4 & 15;
            bf16x4 u;
            u[0] = vt[dv][s4 * 4 + 0]; u[1] = vt[dv][s4 * 4 + 1];
            u[2] = vt[dv][s4 * 4 + 2]; u[3] = vt[dv][s4 * 4 + 3];
            *(bf16x4*)(vT + ((size_t)(bb * DD + dv)) * SS + s0 + s4 * 4) = u;
        }
    }
}

// Attention: block = 32 q-rows of one batch, 4 waves each own S/4 of the keys.
// No max-subtraction needed: |score*log2e/8| <= 0.181 -> exp2 arg tiny, stable.
// P transposed per-wave through private swizzled LDS (no barriers in main loop).
__global__ __launch_bounds__(256) void k_attn(
    const bf16* __restrict__ qn, const bf16* __restrict__ kn,
    const bf16* __restrict__ vT, float* __restrict__ out)
{
    int b  = blockIdx.y;
    int q0 = blockIdx.x * 32;
    int lane = threadIdx.x & 63, wid = threadIdx.x >> 6;
    int lr = lane & 15, lk = lane >> 4;

    __shared__ bf16  p_all[4][32 * 64];      // 16 KiB, wave-private quarters
    __shared__ float num_lds[4][32][68];     // 34.8 KiB
    __shared__ float den_lds[4][32];
    bf16* p_lds = &p_all[wid][0];

    // hoist Q A-fragments: [rf][kd], row = q0+rf*16+lr, k = kd*32+lk*8..+8
    const bf16* qb = qn + ((size_t)(b * SS + q0 + lr)) * DD + lk * 8;
    bf16x8 qf[2][2];
    qf[0][0] = *(const bf16x8*)(qb);
    qf[0][1] = *(const bf16x8*)(qb + 32);
    qf[1][0] = *(const bf16x8*)(qb + 16 * DD);
    qf[1][1] = *(const bf16x8*)(qb + 16 * DD + 32);

    const bf16* kb = kn + (size_t)b * SS * DD;
    const bf16* vb = vT + (size_t)b * DD * SS;

    f32x4 oacc[2][4] = {};
    f32x4 den[2]     = {};

    int sbeg = wid * (SS / 4);
    for (int s = sbeg; s < sbeg + SS / 4; s += 64) {
        // ---- QK^T: scores[32q][64s] ----
        f32x4 sacc[2][4] = {};
        #pragma unroll
        for (int cf = 0; cf < 4; ++cf) {
            const bf16* kp = kb + (size_t)(s + cf * 16 + lr) * DD + lk * 8;
            bf16x8 k0 = *(const bf16x8*)(kp);
            bf16x8 k1 = *(const bf16x8*)(kp + 32);
            sacc[0][cf] = MFMA16(qf[0][0], k0, sacc[0][cf], 0, 0, 0);
            sacc[0][cf] = MFMA16(qf[0][1], k1, sacc[0][cf], 0, 0, 0);
            sacc[1][cf] = MFMA16(qf[1][0], k0, sacc[1][cf], 0, 0, 0);
            sacc[1][cf] = MFMA16(qf[1][1], k1, sacc[1][cf], 0, 0, 0);
        }
        // ---- p = exp2(score); den += p; transpose p via swizzled LDS ----
        #pragma unroll
        for (int rf = 0; rf < 2; ++rf)
            #pragma unroll
            for (int reg = 0; reg < 4; ++reg) {
                int prow = rf * 16 + lk * 4 + reg;
                int swz  = (prow & 7) << 4;
                #pragma unroll
                for (int cf = 0; cf < 4; ++cf) {
                    float p = __builtin_amdgcn_exp2f(sacc[rf][cf][reg]);
                    den[rf][reg] += p;
                    *(bf16*)((char*)p_lds + prow * 128 + ((((cf * 16 + lr) * 2)) ^ swz)) = (bf16)p;
                }
            }
        __builtin_amdgcn_sched_barrier(0);   // keep DS reads after DS writes
        // ---- read P as A-fragments ----
        bf16x8 pf[2][2];
        #pragma unroll
        for (int rf = 0; rf < 2; ++rf)
            #pragma unroll
            for (int ks = 0; ks < 2; ++ks) {
                int prow = rf * 16 + lr;
                int swz  = (prow & 7) << 4;
                pf[rf][ks] = *(const bf16x8*)((char*)p_lds + prow * 128
                               + (((ks * 32 + lk * 8) * 2) ^ swz));
            }
        // ---- PV: out[32q][64dv] += P[32q][64s] @ V[64s][64dv] (B from vT) ----
        #pragma unroll
        for (int cf = 0; cf < 4; ++cf) {
            const bf16* vp = vb + (size_t)(cf * 16 + lr) * SS + s + lk * 8;
            bf16x8 v0 = *(const bf16x8*)(vp);
            bf16x8 v1 = *(const bf16x8*)(vp + 32);
            oacc[0][cf] = MFMA16(pf[0][0], v0, oacc[0][cf], 0, 0, 0);
            oacc[0][cf] = MFMA16(pf[0][1], v1, oacc[0][cf], 0, 0, 0);
            oacc[1][cf] = MFMA16(pf[1][0], v0, oacc[1][cf], 0, 0, 0);
            oacc[1][cf] = MFMA16(pf[1][1], v1, oacc[1][cf], 0, 0, 0);
        }
    }

    // ---- den lane-reduce + dump partials to LDS ----
    #pragma unroll
    for (int rf = 0; rf < 2; ++rf)
        #pragma unroll
        for (int reg = 0; reg < 4; ++reg) {
            float d = den[rf][reg];
            d += __shfl_xor(d, 1); d += __shfl_xor(d, 2);
            d += __shfl_xor(d, 4); d += __shfl_xor(d, 8);
            if (lr == 0) den_lds[wid][rf * 16 + lk * 4 + reg] = d;
            #pragma unroll
            for (int cf = 0; cf < 4; ++cf)
                num_lds[wid][rf * 16 + lk * 4 + reg][cf * 16 + lr] = oacc[rf][cf][reg];
        }
    __syncthreads();

    // ---- combine 4 wave-partials, divide, store ----
    float* ob = out + ((size_t)b * SS + q0) * DD;
    #pragma unroll
    for (int j = 0; j < 8; ++j) {
        int e = threadIdx.x + j * 256;       // 0..2047
        int q = e >> 6, dv = e & 63;
        float n = num_lds[0][q][dv] + num_lds[1][q][dv] + num_lds[2][q][dv] + num_lds[3][q][dv];
        float d = den_lds[0][q] + den_lds[1][q] + den_lds[2][q] + den_lds[3][q];
        ob[e] = n / d;
    }
}

extern "C" void kernel_launch(void* const* d_in, const int* in_sizes, int n_in,
                              void* d_out, int out_size, void* d_ws, size_t ws_size,
                              hipStream_t stream) {
    const float* Xq = (const float*)d_in[0];
    const float* Xk = (const float*)d_in[1];
    const float* Xv = (const float*)d_in[2];
    const float* Wq = (const float*)d_in[3];
    const float* bq = (const float*)d_in[4];
    const float* Wk = (const float*)d_in[5];
    const float* bk = (const float*)d_in[6];
    const float* Wv = (const float*)d_in[7];
    const float* bv = (const float*)d_in[8];

    bf16* ws = (bf16*)d_ws;
    bf16* wt = ws;                               // 3*64*768
    bf16* qn = ws + 3 * DD * DIN;                // 16384*64
    bf16* kn = qn + (size_t)NROWS * DD;
    bf16* vT = kn + (size_t)NROWS * DD;
    float* o = (float*)d_out;

    hipLaunchKernelGGL(k_wt,   dim3(12, 3),  dim3(256), 0, stream, Wq, Wk, Wv, wt);
    hipLaunchKernelGGL(k_proj, dim3(256, 3), dim3(256), 0, stream,
                       Xq, Xk, Xv, bq, bk, bv, wt, qn, kn, vT);
    hipLaunchKernelGGL(k_attn, dim3(64, 8),  dim3(256), 0, stream, qn, kn, vT, o);
}